// Round 6
// baseline (3736.738 us; speedup 1.0000x reference)
//
#include <hip/hip_runtime.h>
#include <stdint.h>

// ResidualVQ on MI355X — round 6: two-pass MFMA prefilter (stall-free pass 1),
// recompute-and-collect pass 2, exact f32 rescore (round-4 contract).
// Contract (proven rounds 4/5): indices match numpy argmin of
// d = fl(fl(t1+nk) - fl(2*dot)), np-exact pairwise sumsq trees, serial
// ascending-k single-accumulator FMA dot, lowest-index ties.
// Prefilter bound: bf16(RNE) est error E <= 0.0078*||r||*||w||; collection
// window delta = 0.02*sqrt(t1)*sqrt(nkmax) + 3e-4 >= 2E -> true argmin always
// collected; exact rescore picks it bit-identically.

#define NQ      8
#define KCODES  1024
#define DIM     256
#define NVEC    65536
#define ROWS    32
#define RST     260      // R row stride (f32), float4-aligned
#define CAP     32       // candidate capacity per row per q

typedef unsigned int u32;
typedef unsigned long long u64;
typedef unsigned short u16;
typedef short bf16x8 __attribute__((ext_vector_type(8)));
typedef float f32x4  __attribute__((ext_vector_type(4)));

__device__ float  g_norms[NQ * KCODES];
__device__ u32    g_nkmax;                 // f32 bits of max ||W_k||^2
__device__ double g_loss;
__device__ __align__(16) u16 g_wb[(size_t)NQ * KCODES * DIM];  // bf16 codebooks

__device__ __forceinline__ u16 bf16rne(float x){
    u32 u = __float_as_uint(x);
    return (u16)((u + 0x7FFFu + ((u >> 16) & 1u)) >> 16);
}

// numpy pairwise sum of squares over 128 contiguous floats (verified round 4)
__device__ __forceinline__ float np_sumsq128(const float* __restrict__ a){
    float r0,r1,r2,r3,r4,r5,r6,r7;
    {
        float4 v0 = *(const float4*)(a);
        float4 v1 = *(const float4*)(a + 4);
        r0 = __fmul_rn(v0.x,v0.x); r1 = __fmul_rn(v0.y,v0.y);
        r2 = __fmul_rn(v0.z,v0.z); r3 = __fmul_rn(v0.w,v0.w);
        r4 = __fmul_rn(v1.x,v1.x); r5 = __fmul_rn(v1.y,v1.y);
        r6 = __fmul_rn(v1.z,v1.z); r7 = __fmul_rn(v1.w,v1.w);
    }
    for (int i = 8; i < 128; i += 8){
        float4 v0 = *(const float4*)(a + i);
        float4 v1 = *(const float4*)(a + i + 4);
        r0 = __fadd_rn(r0, __fmul_rn(v0.x,v0.x));
        r1 = __fadd_rn(r1, __fmul_rn(v0.y,v0.y));
        r2 = __fadd_rn(r2, __fmul_rn(v0.z,v0.z));
        r3 = __fadd_rn(r3, __fmul_rn(v0.w,v0.w));
        r4 = __fadd_rn(r4, __fmul_rn(v1.x,v1.x));
        r5 = __fadd_rn(r5, __fmul_rn(v1.y,v1.y));
        r6 = __fadd_rn(r6, __fmul_rn(v1.z,v1.z));
        r7 = __fadd_rn(r7, __fmul_rn(v1.w,v1.w));
    }
    return __fadd_rn(__fadd_rn(__fadd_rn(r0,r1), __fadd_rn(r2,r3)),
                     __fadd_rn(__fadd_rn(r4,r5), __fadd_rn(r6,r7)));
}

__global__ void vq_zero(){ g_loss = 0.0; g_nkmax = 0u; }

__global__ void vq_norms_np(const float* __restrict__ cb){
    int row = blockIdx.x * 256 + threadIdx.x;               // 8192 rows
    const float* a = cb + (size_t)row * DIM;
    float n = __fadd_rn(np_sumsq128(a), np_sumsq128(a + 128));
    g_norms[row] = n;
    atomicMax(&g_nkmax, __float_as_uint(n));                // n > 0
}

__global__ void vq_prep_wb(const float* __restrict__ cb){
    size_t e4 = (size_t)blockIdx.x * 256 + threadIdx.x;     // 524288 threads
    float4 v = *(const float4*)(cb + e4 * 4);
    u64 P =  (u64)bf16rne(v.x)
          | ((u64)bf16rne(v.y) << 16)
          | ((u64)bf16rne(v.z) << 32)
          | ((u64)bf16rne(v.w) << 48);
    ((u64*)g_wb)[e4] = P;
}

__device__ __forceinline__ void ldsAtomicMinU64(u64* p, u64 v){
    u64 old = *p;
    while (v < old){
        u64 a = old;
        old = atomicCAS(p, a, v);
        if (old == a) break;
    }
}

// one 16x16 tile of estimated distances: dest[j] for rows lg*4+j, code l15
__device__ __forceinline__ void tile_dests(const bf16x8* __restrict__ a,
                                           const u16* __restrict__ wbq,
                                           const float* __restrict__ nt,
                                           int code0, int l15, int lg,
                                           const float* __restrict__ t1r,
                                           float* __restrict__ dest){
    const bf16x8* bp = (const bf16x8*)(wbq + (size_t)(code0 + l15) * DIM + lg * 8);
    f32x4 accA = {0.f,0.f,0.f,0.f}, accB = {0.f,0.f,0.f,0.f};
#pragma unroll
    for (int ks = 0; ks < 4; ++ks){
        accA = __builtin_amdgcn_mfma_f32_16x16x32_bf16(a[ks],     bp[ks * 4],       accA, 0, 0, 0);
        accB = __builtin_amdgcn_mfma_f32_16x16x32_bf16(a[ks + 4], bp[(ks + 4) * 4], accB, 0, 0, 0);
    }
    float nk = nt[code0 + l15];
#pragma unroll
    for (int j = 0; j < 4; ++j)
        dest[j] = (t1r[j] + nk) - 2.0f * (accA[j] + accB[j]);
}

__global__ __launch_bounds__(256, 3)
void vq_main(const float* __restrict__ z, const float* __restrict__ cb,
             float* __restrict__ out)
{
    __shared__ __align__(16) float R[ROWS * RST];    // 33,280 B
    __shared__ float nt[KCODES];                     //  4,096 B
    __shared__ float t1[ROWS];
    __shared__ float rowMinHalf[ROWS * 2];
    __shared__ float rowThr[ROWS];
    __shared__ u32   cnt[ROWS];
    __shared__ u16   cand[ROWS * CAP];               //  2,048 B
    __shared__ u64   bestKey[ROWS];
    __shared__ int   bestk[ROWS];
    __shared__ int   idxs[ROWS * NQ];
    __shared__ int   off[ROWS + 1];
    __shared__ int   totalS, ovf;                    // total ~42 KB -> 3 blk/CU

    const int tid     = threadIdx.x;
    const int rowbase = blockIdx.x * ROWS;
    const int wid     = tid >> 6, lane = tid & 63;
    const int rg      = wid & 1;            // row-group: rows rg*16..+15
    const int ch      = wid >> 1;           // code half: [ch*512, ch*512+512)
    const int l15     = lane & 15, lg = lane >> 4;
    const int urow    = tid >> 3, us = tid & 7;   // residual-update map
    double lossAcc = 0.0;

    // z tile -> R
#pragma unroll
    for (int l = 0; l < 8; ++l){
        int i = l * 256 + tid;              // 2048 f4 = 32 rows x 64
        int row = i >> 6, c4 = i & 63;
        float4 v = *(const float4*)(z + (size_t)(rowbase + row) * DIM + c4 * 4);
        *(float4*)(R + row * RST + c4 * 4) = v;
    }
    __syncthreads();

    const float sqnkmax = sqrtf(__uint_as_float(g_nkmax));

    for (int q = 0; q < NQ; ++q){
        // ---- t1 (np-exact) + nt stage + A-frag build (registers) ----
        if (tid < 64){
            float s = np_sumsq128(R + (tid >> 1) * RST + (tid & 1) * 128);
            float o = __shfl_xor(s, 1);
            if ((tid & 1) == 0) t1[tid >> 1] = __fadd_rn(s, o);
        }
        *(float4*)(nt + tid * 4) = *(const float4*)(g_norms + q * KCODES + tid * 4);

        bf16x8 a[8];
        {
            const float* rr = R + (rg * 16 + l15) * RST + lg * 8;
#pragma unroll
            for (int ks = 0; ks < 8; ++ks){
                float4 v0 = *(const float4*)(rr + ks * 32);
                float4 v1 = *(const float4*)(rr + ks * 32 + 4);
                union { bf16x8 v; u64 p[2]; } u;
                u.p[0] =  (u64)bf16rne(v0.x)        | ((u64)bf16rne(v0.y) << 16)
                       | ((u64)bf16rne(v0.z) << 32) | ((u64)bf16rne(v0.w) << 48);
                u.p[1] =  (u64)bf16rne(v1.x)        | ((u64)bf16rne(v1.y) << 16)
                       | ((u64)bf16rne(v1.z) << 32) | ((u64)bf16rne(v1.w) << 48);
                a[ks] = u.v;
            }
        }
        __syncthreads();
        if (tid == 0 && q > 0)
            for (int r = 0; r < ROWS; ++r) lossAcc += (double)t1[r];

        float t1r[4];
#pragma unroll
        for (int j = 0; j < 4; ++j) t1r[j] = t1[rg * 16 + lg * 4 + j];
        const u16* wbq = g_wb + (size_t)q * KCODES * DIM;

        // ---- pass 1: pure register min over all 32 tiles ----
        float minv[4];
#pragma unroll
        for (int j = 0; j < 4; ++j) minv[j] = __int_as_float(0x7f800000);
#pragma unroll 2
        for (int tile = 0; tile < 32; ++tile){
            float dst[4];
            tile_dests(a, wbq, nt, ch * 512 + tile * 16, l15, lg, t1r, dst);
#pragma unroll
            for (int j = 0; j < 4; ++j) minv[j] = fminf(minv[j], dst[j]);
        }
#pragma unroll
        for (int o = 1; o < 16; o <<= 1){
#pragma unroll
            for (int j = 0; j < 4; ++j)
                minv[j] = fminf(minv[j], __shfl_xor(minv[j], o));
        }
        if (l15 == 0){
#pragma unroll
            for (int j = 0; j < 4; ++j)
                rowMinHalf[(rg * 16 + lg * 4 + j) * 2 + ch] = minv[j];
        }
        __syncthreads();

        // ---- combine halves -> final threshold; reset state ----
        if (tid < ROWS){
            float m = fminf(rowMinHalf[tid * 2], rowMinHalf[tid * 2 + 1]);
            rowThr[tid]  = m + 0.02f * sqrtf(t1[tid]) * sqnkmax + 3e-4f;
            cnt[tid]     = 0u;
            bestKey[tid] = ~0ull;
        }
        __syncthreads();

        // ---- pass 2: recompute, collect candidates vs final threshold ----
#pragma unroll 2
        for (int tile = 0; tile < 32; ++tile){
            int code0 = ch * 512 + tile * 16;
            float dst[4];
            tile_dests(a, wbq, nt, code0, l15, lg, t1r, dst);
#pragma unroll
            for (int j = 0; j < 4; ++j){
                int row = rg * 16 + lg * 4 + j;
                if (dst[j] <= rowThr[row]){
                    u32 slot = atomicAdd(&cnt[row], 1u);
                    if (slot < CAP) cand[row * CAP + slot] = (u16)(code0 + l15);
                }
            }
        }
        __syncthreads();

        // ---- task offsets ----
        if (tid == 0){
            int tot = 0, ov = 0;
            for (int r = 0; r < ROWS; ++r){
                off[r] = tot;
                int c = (int)cnt[r];
                if (c > CAP){ c = CAP; ov = 1; }
                tot += c;
            }
            off[ROWS] = tot; totalS = tot; ovf = ov;
        }
        __syncthreads();

        // ---- exact rescore (round-4-identical serial FMA chain) ----
        int nT = totalS;
        for (int t = tid; t < nT; t += 256){
            int r = 0;
            while (off[r + 1] <= t) ++r;
            int k = (int)cand[r * CAP + (t - off[r])];
            const float* wr = cb + ((size_t)q * KCODES + k) * DIM;
            const float* rr = R + r * RST;
            float dot = 0.f;
#pragma unroll 4
            for (int i = 0; i < 64; ++i){
                float4 rv = *(const float4*)(rr + i * 4);
                float4 wv = *(const float4*)(wr + i * 4);
                dot = __builtin_fmaf(rv.x, wv.x, dot);
                dot = __builtin_fmaf(rv.y, wv.y, dot);
                dot = __builtin_fmaf(rv.z, wv.z, dot);
                dot = __builtin_fmaf(rv.w, wv.w, dot);
            }
            float d = __fsub_rn(__fadd_rn(t1[r], nt[k]), __fmul_rn(2.0f, dot));
            ldsAtomicMinU64(&bestKey[r], ((u64)__float_as_uint(d) << 32) | (u32)k);
        }
        if (ovf){   // correctness fallback; never taken in practice
            for (int r = 0; r < ROWS; ++r){
                if (cnt[r] > CAP){
                    for (int k = tid; k < KCODES; k += 256){
                        const float* wr = cb + ((size_t)q * KCODES + k) * DIM;
                        const float* rr = R + r * RST;
                        float dot = 0.f;
                        for (int i = 0; i < 64; ++i){
                            float4 rv = *(const float4*)(rr + i * 4);
                            float4 wv = *(const float4*)(wr + i * 4);
                            dot = __builtin_fmaf(rv.x, wv.x, dot);
                            dot = __builtin_fmaf(rv.y, wv.y, dot);
                            dot = __builtin_fmaf(rv.z, wv.z, dot);
                            dot = __builtin_fmaf(rv.w, wv.w, dot);
                        }
                        float d = __fsub_rn(__fadd_rn(t1[r], nt[k]), __fmul_rn(2.0f, dot));
                        ldsAtomicMinU64(&bestKey[r], ((u64)__float_as_uint(d) << 32) | (u32)k);
                    }
                }
            }
        }
        __syncthreads();
        if (tid < ROWS){
            int k = (int)(bestKey[tid] & 0xFFFFFFFFull);
            bestk[tid] = k;
            idxs[tid * NQ + q] = k;
        }
        __syncthreads();

        // r_new = fl(r - fl(r + fl(zq - r)))
        {
            int k = bestk[urow];
            const float* wrow = cb + ((size_t)q * KCODES + k) * DIM;
#pragma unroll
            for (int j = 0; j < 8; ++j){
                int d0 = us * 4 + j * 32;
                float4 r4 = *(float4*)(R + urow * RST + d0);
                float4 wv = *(const float4*)(wrow + d0);
                float4 rn;
                rn.x = __fsub_rn(r4.x, __fadd_rn(r4.x, __fsub_rn(wv.x, r4.x)));
                rn.y = __fsub_rn(r4.y, __fadd_rn(r4.y, __fsub_rn(wv.y, r4.y)));
                rn.z = __fsub_rn(r4.z, __fadd_rn(r4.z, __fsub_rn(wv.z, r4.z)));
                rn.w = __fsub_rn(r4.w, __fadd_rn(r4.w, __fsub_rn(wv.w, r4.w)));
                *(float4*)(R + urow * RST + d0) = rn;
            }
        }
        __syncthreads();
    }

    // final residual norm -> loss
    if (tid < 64){
        float s = np_sumsq128(R + (tid >> 1) * RST + (tid & 1) * 128);
        float o = __shfl_xor(s, 1);
        if ((tid & 1) == 0) t1[tid >> 1] = __fadd_rn(s, o);
    }
    __syncthreads();
    if (tid == 0){
        for (int r = 0; r < ROWS; ++r) lossAcc += (double)t1[r];
        atomicAdd(&g_loss, lossAcc);
    }

    // indices out (f32)
    {
        int row = tid >> 3, qq = tid & 7;
        size_t n = (size_t)rowbase + row;
        out[(size_t)NVEC * DIM + n * NQ + qq] = (float)idxs[row * NQ + qq];
    }
    // recon out (f32): z - r_final
    {
        size_t n = (size_t)rowbase + urow;
#pragma unroll
        for (int j = 0; j < 8; ++j){
            int d0 = us * 4 + j * 32;
            float4 zv = *(const float4*)(z + n * DIM + d0);
            float4 rv = *(const float4*)(R + urow * RST + d0);
            float4 ov;
            ov.x = __fsub_rn(zv.x, rv.x);
            ov.y = __fsub_rn(zv.y, rv.y);
            ov.z = __fsub_rn(zv.z, rv.z);
            ov.w = __fsub_rn(zv.w, rv.w);
            *(float4*)(out + n * DIM + d0) = ov;
        }
    }
}

__global__ void vq_loss_final(float* __restrict__ out){
    if (threadIdx.x == 0 && blockIdx.x == 0){
        double m = 1.25 * g_loss / ((double)NVEC * (double)DIM);
        out[(size_t)NVEC * DIM + (size_t)NVEC * NQ] = (float)m;
    }
}

extern "C" void kernel_launch(void* const* d_in, const int* in_sizes, int n_in,
                              void* d_out, int out_size, void* d_ws, size_t ws_size,
                              hipStream_t stream) {
    (void)in_sizes; (void)n_in; (void)out_size; (void)d_ws; (void)ws_size;
    const float* z  = (const float*)d_in[0];
    const float* cb = (const float*)d_in[1];
    float* out = (float*)d_out;

    hipLaunchKernelGGL(vq_zero,       dim3(1),    dim3(1),   0, stream);
    hipLaunchKernelGGL(vq_norms_np,   dim3(32),   dim3(256), 0, stream, cb);
    hipLaunchKernelGGL(vq_prep_wb,    dim3(2048), dim3(256), 0, stream, cb);
    hipLaunchKernelGGL(vq_main,       dim3(NVEC / ROWS), dim3(256), 0, stream, z, cb, out);
    hipLaunchKernelGGL(vq_loss_final, dim3(1),    dim3(64),  0, stream, out);
}

// Round 7
// 1505.441 us; speedup vs baseline: 2.4822x; 2.4822x over previous
//
#include <hip/hip_runtime.h>
#include <stdint.h>

// ResidualVQ on MI355X — round 7: LDS-staged bf16 codebook (global_load_lds),
// wave = 32 rows x 16 codes, single-pass stale-threshold prefilter,
// exact f32 rescore (round-4 contract, proven rounds 4/5/6).
// g_wb is stored PRE-PERMUTED (16B slot s -> s ^ (code&7) within each 512B
// code row) so linear global_load_lds staging + XOR-read gives conflict-free
// ds_read_b128 B-fragments.

#define NQ      8
#define KCODES  1024
#define DIM     256
#define NVEC    65536
#define ROWS    32
#define RST     260      // R row stride (f32): 260%32=4 -> 2-way (free) on frag reads
#define CCH     32       // codes per staged chunk (16 KB)
#define CAP     32       // candidate capacity per row per q

typedef unsigned int u32;
typedef unsigned long long u64;
typedef unsigned short u16;
typedef short bf16x8 __attribute__((ext_vector_type(8)));
typedef float f32x4  __attribute__((ext_vector_type(4)));

__device__ float  g_norms[NQ * KCODES];
__device__ u32    g_nkmax;
__device__ double g_loss;
__device__ __align__(16) u16 g_wb[(size_t)NQ * KCODES * DIM];  // permuted bf16

__device__ __forceinline__ u16 bf16rne(float x){
    u32 u = __float_as_uint(x);
    return (u16)((u + 0x7FFFu + ((u >> 16) & 1u)) >> 16);
}

__device__ __forceinline__ void gload_lds16(const void* g, void* l){
    __builtin_amdgcn_global_load_lds(
        (const __attribute__((address_space(1))) u32*)g,
        (__attribute__((address_space(3))) u32*)l, 16, 0, 0);
}

// numpy pairwise sum of squares over 128 contiguous floats (verified round 4)
__device__ __forceinline__ float np_sumsq128(const float* __restrict__ a){
    float r0,r1,r2,r3,r4,r5,r6,r7;
    {
        float4 v0 = *(const float4*)(a);
        float4 v1 = *(const float4*)(a + 4);
        r0 = __fmul_rn(v0.x,v0.x); r1 = __fmul_rn(v0.y,v0.y);
        r2 = __fmul_rn(v0.z,v0.z); r3 = __fmul_rn(v0.w,v0.w);
        r4 = __fmul_rn(v1.x,v1.x); r5 = __fmul_rn(v1.y,v1.y);
        r6 = __fmul_rn(v1.z,v1.z); r7 = __fmul_rn(v1.w,v1.w);
    }
    for (int i = 8; i < 128; i += 8){
        float4 v0 = *(const float4*)(a + i);
        float4 v1 = *(const float4*)(a + i + 4);
        r0 = __fadd_rn(r0, __fmul_rn(v0.x,v0.x));
        r1 = __fadd_rn(r1, __fmul_rn(v0.y,v0.y));
        r2 = __fadd_rn(r2, __fmul_rn(v0.z,v0.z));
        r3 = __fadd_rn(r3, __fmul_rn(v0.w,v0.w));
        r4 = __fadd_rn(r4, __fmul_rn(v1.x,v1.x));
        r5 = __fadd_rn(r5, __fmul_rn(v1.y,v1.y));
        r6 = __fadd_rn(r6, __fmul_rn(v1.z,v1.z));
        r7 = __fadd_rn(r7, __fmul_rn(v1.w,v1.w));
    }
    return __fadd_rn(__fadd_rn(__fadd_rn(r0,r1), __fadd_rn(r2,r3)),
                     __fadd_rn(__fadd_rn(r4,r5), __fadd_rn(r6,r7)));
}

__global__ void vq_zero(){ g_loss = 0.0; g_nkmax = 0u; }

__global__ void vq_norms_np(const float* __restrict__ cb){
    int row = blockIdx.x * 256 + threadIdx.x;               // 8192 rows
    const float* a = cb + (size_t)row * DIM;
    float n = __fadd_rn(np_sumsq128(a), np_sumsq128(a + 128));
    g_norms[row] = n;
    atomicMax(&g_nkmax, __float_as_uint(n));
}

// bf16 convert + intra-row 16B-slot permutation: slot s -> s ^ (code&7)
__global__ void vq_prep_wb(const float* __restrict__ cb){
    int t = blockIdx.x * 256 + threadIdx.x;     // 262,144 = 8192 codes x 32 slots
    int code = t >> 5, s = t & 31;
    const float* src = cb + (size_t)code * DIM + s * 8;
    float4 v0 = *(const float4*)(src);
    float4 v1 = *(const float4*)(src + 4);
    u64 P0 =  (u64)bf16rne(v0.x)        | ((u64)bf16rne(v0.y) << 16)
           | ((u64)bf16rne(v0.z) << 32) | ((u64)bf16rne(v0.w) << 48);
    u64 P1 =  (u64)bf16rne(v1.x)        | ((u64)bf16rne(v1.y) << 16)
           | ((u64)bf16rne(v1.z) << 32) | ((u64)bf16rne(v1.w) << 48);
    u64* dst = (u64*)(g_wb + (size_t)code * DIM + ((s ^ (code & 7)) << 3));
    dst[0] = P0; dst[1] = P1;
}

__device__ __forceinline__ void ldsAtomicMinU64(u64* p, u64 v){
    u64 old = *p;
    while (v < old){
        u64 a = old;
        old = atomicCAS(p, a, v);
        if (old == a) break;
    }
}

__global__ __launch_bounds__(128)
void vq_main(const float* __restrict__ z, const float* __restrict__ cb,
             float* __restrict__ out)
{
    __shared__ __align__(16) float R[ROWS * RST];    // 33,280 B
    __shared__ __align__(16) u16   Wst[CCH * DIM];   // 16,384 B staged chunk
    __shared__ float t1[ROWS];
    __shared__ u32   rminU[ROWS];
    __shared__ u32   cnt[ROWS];
    __shared__ u16   cand[ROWS * CAP];               //  2,048 B
    __shared__ u64   bestKey[ROWS];
    __shared__ int   bestk[ROWS];
    __shared__ int   idxs[ROWS * NQ];
    __shared__ int   off[ROWS + 1];
    __shared__ int   totalS, ovf;                    // ~53.6 KB -> 3 blocks/CU

    const int tid     = threadIdx.x;                 // 128 threads, 2 waves
    const int rowbase = blockIdx.x * ROWS;
    const int ct      = tid >> 6;                    // wave id = codetile 0/1
    const int lane    = tid & 63;
    const int l15     = lane & 15, lg = lane >> 4;
    const int urow    = tid >> 2, us = tid & 3;      // update map: 4 thr/row
    double lossAcc = 0.0;

    // z tile -> R
#pragma unroll
    for (int l = 0; l < 16; ++l){
        int i = l * 128 + tid;              // 2048 f4 = 32 rows x 64
        int row = i >> 6, c4 = i & 63;
        float4 v = *(const float4*)(z + (size_t)(rowbase + row) * DIM + c4 * 4);
        *(float4*)(R + row * RST + c4 * 4) = v;
    }
    __syncthreads();

    const float sqnkmax = sqrtf(__uint_as_float(g_nkmax));

    for (int q = 0; q < NQ; ++q){
        // ---- t1 (np-exact), state reset ----
        if (tid < 64){
            float s = np_sumsq128(R + (tid >> 1) * RST + (tid & 1) * 128);
            float o = __shfl_xor(s, 1);
            if ((tid & 1) == 0) t1[tid >> 1] = __fadd_rn(s, o);
        }
        if (tid < ROWS){
            rminU[tid]   = 0x7f800000u;
            cnt[tid]     = 0u;
            bestKey[tid] = ~0ull;
        }
        __syncthreads();
        if (tid == 0 && q > 0)
            for (int r = 0; r < ROWS; ++r) lossAcc += (double)t1[r];

        // A-frags for ALL 32 rows (both rowtiles), 8 k-steps, in registers
        bf16x8 a[2][8];
#pragma unroll
        for (int rt = 0; rt < 2; ++rt){
            const float* rr = R + (rt * 16 + l15) * RST + lg * 8;
#pragma unroll
            for (int ks = 0; ks < 8; ++ks){
                float4 v0 = *(const float4*)(rr + ks * 32);
                float4 v1 = *(const float4*)(rr + ks * 32 + 4);
                union { bf16x8 v; u64 p[2]; } u;
                u.p[0] =  (u64)bf16rne(v0.x)        | ((u64)bf16rne(v0.y) << 16)
                       | ((u64)bf16rne(v0.z) << 32) | ((u64)bf16rne(v0.w) << 48);
                u.p[1] =  (u64)bf16rne(v1.x)        | ((u64)bf16rne(v1.y) << 16)
                       | ((u64)bf16rne(v1.z) << 32) | ((u64)bf16rne(v1.w) << 48);
                a[rt][ks] = u.v;
            }
        }
        float t1r[2][4], delta[2][4];
#pragma unroll
        for (int rt = 0; rt < 2; ++rt)
#pragma unroll
            for (int j = 0; j < 4; ++j){
                t1r[rt][j]   = t1[rt * 16 + lg * 4 + j];
                delta[rt][j] = 0.02f * sqrtf(t1r[rt][j]) * sqnkmax + 3e-4f;
            }

        const char* wbq = (const char*)g_wb + (size_t)q * KCODES * DIM * 2;
        const int key = l15 & 7;

        // ---- chunk loop: stage 32 codes -> LDS, MFMA, stale-threshold collect.
        // chunks 0..3 swept min-only first, revisited at tt 32..35.
        for (int tt = 0; tt < 36; ++tt){
            int  cc      = (tt < 32) ? tt : (tt - 32);
            bool collect = (tt >= 4);
            // stage 16 KB: 8 x (128 thr x 16 B), linear (g_wb pre-permuted)
            {
                const char* src = wbq + (size_t)cc * (CCH * DIM * 2);
                char* dstb = (char*)Wst;
#pragma unroll
                for (int r = 0; r < 8; ++r){
                    int o = (r * 128 + tid) * 16;
                    gload_lds16(src + o, dstb + o);
                }
            }
            __syncthreads();

            int   codeL = ct * 16 + l15;            // chunk-local code
            float nk    = g_norms[q * KCODES + cc * CCH + codeL];
            const u16* wrow = Wst + codeL * DIM;
            f32x4 accA0 = {0,0,0,0}, accB0 = {0,0,0,0};
            f32x4 accA1 = {0,0,0,0}, accB1 = {0,0,0,0};
#pragma unroll
            for (int ks = 0; ks < 4; ++ks){
                bf16x8 blo = *(const bf16x8*)(wrow + (((ks * 4 + lg) ^ key) << 3));
                bf16x8 bhi = *(const bf16x8*)(wrow + ((((ks + 4) * 4 + lg) ^ key) << 3));
                accA0 = __builtin_amdgcn_mfma_f32_16x16x32_bf16(a[0][ks],     blo, accA0, 0, 0, 0);
                accB0 = __builtin_amdgcn_mfma_f32_16x16x32_bf16(a[0][ks + 4], bhi, accB0, 0, 0, 0);
                accA1 = __builtin_amdgcn_mfma_f32_16x16x32_bf16(a[1][ks],     blo, accA1, 0, 0, 0);
                accB1 = __builtin_amdgcn_mfma_f32_16x16x32_bf16(a[1][ks + 4], bhi, accB1, 0, 0, 0);
            }
            int codeg = cc * CCH + codeL;           // code id within q
#pragma unroll
            for (int rt = 0; rt < 2; ++rt){
                f32x4 sA = rt ? accA1 : accA0, sB = rt ? accB1 : accB0;
#pragma unroll
                for (int j = 0; j < 4; ++j){
                    float dest = (t1r[rt][j] + nk) - 2.0f * (sA[j] + sB[j]);
                    int   row  = rt * 16 + lg * 4 + j;
                    u32   curb = rminU[row];
                    float curf = __uint_as_float(curb);
                    if (dest < curf) atomicMin(&rminU[row], __float_as_uint(dest));
                    if (collect && dest <= curf + delta[rt][j]){
                        u32 slot = atomicAdd(&cnt[row], 1u);
                        if (slot < CAP) cand[row * CAP + slot] = (u16)codeg;
                    }
                }
            }
            __syncthreads();    // Wst consumed; safe to restage
        }

        // ---- task offsets ----
        if (tid == 0){
            int tot = 0, ov = 0;
            for (int r = 0; r < ROWS; ++r){
                off[r] = tot;
                int c = (int)cnt[r];
                if (c > CAP){ c = CAP; ov = 1; }
                tot += c;
            }
            off[ROWS] = tot; totalS = tot; ovf = ov;
        }
        __syncthreads();

        // ---- exact rescore (round-4-identical serial FMA chain) ----
        int nT = totalS;
        for (int t = tid; t < nT; t += 128){
            int r = 0;
            while (off[r + 1] <= t) ++r;
            int k = (int)cand[r * CAP + (t - off[r])];
            const float* wr = cb + ((size_t)q * KCODES + k) * DIM;
            const float* rr = R + r * RST;
            float dot = 0.f;
#pragma unroll 4
            for (int i = 0; i < 64; ++i){
                float4 rv = *(const float4*)(rr + i * 4);
                float4 wv = *(const float4*)(wr + i * 4);
                dot = __builtin_fmaf(rv.x, wv.x, dot);
                dot = __builtin_fmaf(rv.y, wv.y, dot);
                dot = __builtin_fmaf(rv.z, wv.z, dot);
                dot = __builtin_fmaf(rv.w, wv.w, dot);
            }
            float d = __fsub_rn(__fadd_rn(t1[r], g_norms[q * KCODES + k]),
                                __fmul_rn(2.0f, dot));
            ldsAtomicMinU64(&bestKey[r], ((u64)__float_as_uint(d) << 32) | (u32)k);
        }
        if (ovf){   // correctness fallback; never taken in practice
            for (int r = 0; r < ROWS; ++r){
                if (cnt[r] > CAP){
                    for (int k = tid; k < KCODES; k += 128){
                        const float* wr = cb + ((size_t)q * KCODES + k) * DIM;
                        const float* rr = R + r * RST;
                        float dot = 0.f;
                        for (int i = 0; i < 64; ++i){
                            float4 rv = *(const float4*)(rr + i * 4);
                            float4 wv = *(const float4*)(wr + i * 4);
                            dot = __builtin_fmaf(rv.x, wv.x, dot);
                            dot = __builtin_fmaf(rv.y, wv.y, dot);
                            dot = __builtin_fmaf(rv.z, wv.z, dot);
                            dot = __builtin_fmaf(rv.w, wv.w, dot);
                        }
                        float d = __fsub_rn(__fadd_rn(t1[r], g_norms[q * KCODES + k]),
                                            __fmul_rn(2.0f, dot));
                        ldsAtomicMinU64(&bestKey[r], ((u64)__float_as_uint(d) << 32) | (u32)k);
                    }
                }
            }
        }
        __syncthreads();
        if (tid < ROWS){
            int k = (int)(bestKey[tid] & 0xFFFFFFFFull);
            bestk[tid] = k;
            idxs[tid * NQ + q] = k;
        }
        __syncthreads();

        // r_new = fl(r - fl(r + fl(zq - r)))
        {
            int k = bestk[urow];
            const float* wrow = cb + ((size_t)q * KCODES + k) * DIM;
#pragma unroll
            for (int j = 0; j < 16; ++j){
                int d0 = us * 4 + j * 16;
                float4 r4 = *(float4*)(R + urow * RST + d0);
                float4 wv = *(const float4*)(wrow + d0);
                float4 rn;
                rn.x = __fsub_rn(r4.x, __fadd_rn(r4.x, __fsub_rn(wv.x, r4.x)));
                rn.y = __fsub_rn(r4.y, __fadd_rn(r4.y, __fsub_rn(wv.y, r4.y)));
                rn.z = __fsub_rn(r4.z, __fadd_rn(r4.z, __fsub_rn(wv.z, r4.z)));
                rn.w = __fsub_rn(r4.w, __fadd_rn(r4.w, __fsub_rn(wv.w, r4.w)));
                *(float4*)(R + urow * RST + d0) = rn;
            }
        }
        __syncthreads();
    }

    // final residual norm -> loss
    if (tid < 64){
        float s = np_sumsq128(R + (tid >> 1) * RST + (tid & 1) * 128);
        float o = __shfl_xor(s, 1);
        if ((tid & 1) == 0) t1[tid >> 1] = __fadd_rn(s, o);
    }
    __syncthreads();
    if (tid == 0){
        for (int r = 0; r < ROWS; ++r) lossAcc += (double)t1[r];
        atomicAdd(&g_loss, lossAcc);
    }

    // indices out (f32)
    for (int e = tid; e < ROWS * NQ; e += 128){
        int row = e >> 3, qq = e & 7;
        out[(size_t)NVEC * DIM + ((size_t)rowbase + row) * NQ + qq] =
            (float)idxs[row * NQ + qq];
    }
    // recon out (f32): z - r_final
    {
        size_t n = (size_t)rowbase + urow;
#pragma unroll
        for (int j = 0; j < 16; ++j){
            int d0 = us * 4 + j * 16;
            float4 zv = *(const float4*)(z + n * DIM + d0);
            float4 rv = *(const float4*)(R + urow * RST + d0);
            float4 ov;
            ov.x = __fsub_rn(zv.x, rv.x);
            ov.y = __fsub_rn(zv.y, rv.y);
            ov.z = __fsub_rn(zv.z, rv.z);
            ov.w = __fsub_rn(zv.w, rv.w);
            *(float4*)(out + n * DIM + d0) = ov;
        }
    }
}

__global__ void vq_loss_final(float* __restrict__ out){
    if (threadIdx.x == 0 && blockIdx.x == 0){
        double m = 1.25 * g_loss / ((double)NVEC * (double)DIM);
        out[(size_t)NVEC * DIM + (size_t)NVEC * NQ] = (float)m;
    }
}

extern "C" void kernel_launch(void* const* d_in, const int* in_sizes, int n_in,
                              void* d_out, int out_size, void* d_ws, size_t ws_size,
                              hipStream_t stream) {
    (void)in_sizes; (void)n_in; (void)out_size; (void)d_ws; (void)ws_size;
    const float* z  = (const float*)d_in[0];
    const float* cb = (const float*)d_in[1];
    float* out = (float*)d_out;

    hipLaunchKernelGGL(vq_zero,       dim3(1),    dim3(1),   0, stream);
    hipLaunchKernelGGL(vq_norms_np,   dim3(32),   dim3(256), 0, stream, cb);
    hipLaunchKernelGGL(vq_prep_wb,    dim3(1024), dim3(256), 0, stream, cb);
    hipLaunchKernelGGL(vq_main,       dim3(NVEC / ROWS), dim3(128), 0, stream, z, cb, out);
    hipLaunchKernelGGL(vq_loss_final, dim3(1),    dim3(64),  0, stream, out);
}